// Round 1
// baseline (1098.832 us; speedup 1.0000x reference)
//
#include <hip/hip_runtime.h>
#include <math.h>

#define BSZ 2
#define SEQ 2048
#define NH 16
#define DH 64
#define DM 1024
#define HD 1024  // NH*DH

// ---------------------------------------------------------------------------
// Kernel 1: fused QKV projection + RoPE, scatter to [B,H,S,Dh] fp32.
// Tiled fp32 GEMM: 64x64 tile, BK=16, 256 threads, 4x4 micro-tile.
// blockIdx.z selects q/k/v (z=2 => v, no rope).
// ---------------------------------------------------------------------------
__global__ __launch_bounds__(256) void qkv_rope_kernel(
    const float* __restrict__ x,
    const float* __restrict__ wq, const float* __restrict__ wk, const float* __restrict__ wv,
    const float* __restrict__ fcos, const float* __restrict__ fsin,
    float* __restrict__ qw, float* __restrict__ kw, float* __restrict__ vw)
{
    const int z = blockIdx.z;
    const float* __restrict__ w = (z == 0) ? wq : (z == 1) ? wk : wv;
    float* __restrict__ outp    = (z == 0) ? qw : (z == 1) ? kw : vw;

    const int m0 = blockIdx.y * 64;   // row block in [B*S]
    const int n0 = blockIdx.x * 64;   // col block in [HD] (exactly one head)
    const int t  = threadIdx.x;
    const int tx = t & 15, ty = t >> 4;
    const int r0 = ty * 4, c0 = tx * 4;

    __shared__ float As[16][64];   // [k][m]
    __shared__ float Bs[16][64];   // [k][n]

    float acc[4][4] = {};

    const int arow = t >> 2;        // 0..63
    const int aq   = (t & 3) * 4;   // 0,4,8,12
    const int brow = t >> 4;        // 0..15
    const int bc   = (t & 15) * 4;  // 0..60

    for (int k0 = 0; k0 < DM; k0 += 16) {
        float4 av = *(const float4*)&x[(size_t)(m0 + arow) * DM + k0 + aq];
        float4 bv = *(const float4*)&w[(size_t)(k0 + brow) * HD + n0 + bc];
        __syncthreads();   // protect previous iteration's reads
        As[aq + 0][arow] = av.x;
        As[aq + 1][arow] = av.y;
        As[aq + 2][arow] = av.z;
        As[aq + 3][arow] = av.w;
        *(float4*)&Bs[brow][bc] = bv;
        __syncthreads();
#pragma unroll
        for (int kk = 0; kk < 16; ++kk) {
            float4 a4 = *(const float4*)&As[kk][r0];
            float4 b4 = *(const float4*)&Bs[kk][c0];
            float avv[4] = {a4.x, a4.y, a4.z, a4.w};
            float bvv[4] = {b4.x, b4.y, b4.z, b4.w};
#pragma unroll
            for (int i = 0; i < 4; ++i)
#pragma unroll
                for (int j = 0; j < 4; ++j)
                    acc[i][j] = fmaf(avv[i], bvv[j], acc[i][j]);
        }
    }

    const int b      = m0 >> 11;      // 2048 rows per batch, 64 | 2048
    const int s_base = (m0 & 2047) + r0;
    const int h      = n0 >> 6;       // tile spans exactly one head

    if (z < 2) {
        // RoPE: cols c0..c0+3 are head dims d = c0..c0+3 (c0 even), pairs
        // (c0,c0+1) -> pair index c0/2, (c0+2,c0+3) -> c0/2+1.
#pragma unroll
        for (int i = 0; i < 4; ++i) {
            int s = s_base + i;
            float cv0 = fcos[s * 32 + (c0 >> 1)];
            float sv0 = fsin[s * 32 + (c0 >> 1)];
            float cv1 = fcos[s * 32 + (c0 >> 1) + 1];
            float sv1 = fsin[s * 32 + (c0 >> 1) + 1];
            float t0 = acc[i][0], t1 = acc[i][1];
            acc[i][0] = t0 * cv0 - t1 * sv0;
            acc[i][1] = t0 * sv0 + t1 * cv0;
            t0 = acc[i][2]; t1 = acc[i][3];
            acc[i][2] = t0 * cv1 - t1 * sv1;
            acc[i][3] = t0 * sv1 + t1 * cv1;
        }
    }

    // store [B,H,S,Dh]
#pragma unroll
    for (int i = 0; i < 4; ++i) {
        int s = s_base + i;
        float4 o = make_float4(acc[i][0], acc[i][1], acc[i][2], acc[i][3]);
        *(float4*)&outp[(((size_t)(b * NH + h) * SEQ) + s) * DH + c0] = o;
    }
}

// ---------------------------------------------------------------------------
// Kernel 2: flash attention (online softmax), fp32.
// One block = one (b,h) x 64-row Q tile. 256 threads, 4x4 micro-tile.
// Q,K staged d-major (QsT[d][r]) so the QK^T loop reads contiguous float4s;
// V natural [c][d]; P via padded LDS for the PV matmul.
// ---------------------------------------------------------------------------
__global__ __launch_bounds__(256) void attn_kernel(
    const float* __restrict__ qw, const float* __restrict__ kw, const float* __restrict__ vw,
    float* __restrict__ ow)
{
    __shared__ float QsT[64][64];   // [d][r]
    __shared__ float KsT[64][64];   // [d][c]
    __shared__ float Vs[64][64];    // [c][d]
    __shared__ float Ps[64][68];    // [r][c], padded (multi-row float4 reads)

    const int t  = threadIdx.x;
    const int tx = t & 15, ty = t >> 4;
    const int r0 = ty * 4, c0 = tx * 4;
    const int q0 = blockIdx.x * 64;
    const int bh = blockIdx.y;

    const float* __restrict__ qb = qw + (size_t)bh * SEQ * DH + (size_t)q0 * DH;
    const float* __restrict__ kb = kw + (size_t)bh * SEQ * DH;
    const float* __restrict__ vb = vw + (size_t)bh * SEQ * DH;

    const int lrow = t >> 4;        // 0..15
    const int lq   = (t & 15) * 4;  // 0..60

    // stage Q, pre-scaled by 1/sqrt(Dh)=0.125
#pragma unroll
    for (int rr = 0; rr < 4; ++rr) {
        int row = lrow + rr * 16;
        float4 v = *(const float4*)&qb[(size_t)row * DH + lq];
        QsT[lq + 0][row] = v.x * 0.125f;
        QsT[lq + 1][row] = v.y * 0.125f;
        QsT[lq + 2][row] = v.z * 0.125f;
        QsT[lq + 3][row] = v.w * 0.125f;
    }

    float m_i[4], l_i[4], O[4][4];
#pragma unroll
    for (int i = 0; i < 4; ++i) {
        m_i[i] = -INFINITY;
        l_i[i] = 0.f;
#pragma unroll
        for (int j = 0; j < 4; ++j) O[i][j] = 0.f;
    }

    for (int j0 = 0; j0 < SEQ; j0 += 64) {
        __syncthreads();   // prev PV reads done before K/V overwrite
#pragma unroll
        for (int rr = 0; rr < 4; ++rr) {
            int row = lrow + rr * 16;
            float4 kv = *(const float4*)&kb[(size_t)(j0 + row) * DH + lq];
            KsT[lq + 0][row] = kv.x;
            KsT[lq + 1][row] = kv.y;
            KsT[lq + 2][row] = kv.z;
            KsT[lq + 3][row] = kv.w;
            float4 vv = *(const float4*)&vb[(size_t)(j0 + row) * DH + lq];
            *(float4*)&Vs[row][lq] = vv;
        }
        __syncthreads();

        // S tile: sij[i][j] = sum_d Q[r0+i][d]*K[c0+j][d]
        float sij[4][4] = {};
#pragma unroll 16
        for (int d = 0; d < 64; ++d) {
            float4 qa = *(const float4*)&QsT[d][r0];
            float4 ka = *(const float4*)&KsT[d][c0];
            float qv[4] = {qa.x, qa.y, qa.z, qa.w};
            float kv[4] = {ka.x, ka.y, ka.z, ka.w};
#pragma unroll
            for (int i = 0; i < 4; ++i)
#pragma unroll
                for (int j = 0; j < 4; ++j)
                    sij[i][j] = fmaf(qv[i], kv[j], sij[i][j]);
        }

        // online softmax per row (row spread over 16 tx lanes)
#pragma unroll
        for (int i = 0; i < 4; ++i) {
            float mx = fmaxf(fmaxf(sij[i][0], sij[i][1]), fmaxf(sij[i][2], sij[i][3]));
#pragma unroll
            for (int off = 1; off < 16; off <<= 1)
                mx = fmaxf(mx, __shfl_xor(mx, off, 64));
            float mnew  = fmaxf(m_i[i], mx);
            float alpha = __expf(m_i[i] - mnew);
            m_i[i] = mnew;
            float rs = 0.f;
#pragma unroll
            for (int j = 0; j < 4; ++j) {
                float p = __expf(sij[i][j] - mnew);
                Ps[r0 + i][c0 + j] = p;
                rs += p;
            }
#pragma unroll
            for (int off = 1; off < 16; off <<= 1)
                rs += __shfl_xor(rs, off, 64);
            l_i[i] = l_i[i] * alpha + rs;
#pragma unroll
            for (int j = 0; j < 4; ++j) O[i][j] *= alpha;
        }
        __syncthreads();   // Ps complete

        // O += P * V   (O cols = d = c0..c0+3)
#pragma unroll 4
        for (int cb = 0; cb < 16; ++cb) {
            float pm[4][4], vm[4][4];
#pragma unroll
            for (int i = 0; i < 4; ++i) {
                float4 p4 = *(const float4*)&Ps[r0 + i][cb * 4];
                pm[i][0] = p4.x; pm[i][1] = p4.y; pm[i][2] = p4.z; pm[i][3] = p4.w;
            }
#pragma unroll
            for (int cc = 0; cc < 4; ++cc) {
                float4 v4 = *(const float4*)&Vs[cb * 4 + cc][c0];
                vm[cc][0] = v4.x; vm[cc][1] = v4.y; vm[cc][2] = v4.z; vm[cc][3] = v4.w;
            }
#pragma unroll
            for (int i = 0; i < 4; ++i)
#pragma unroll
                for (int cc = 0; cc < 4; ++cc)
#pragma unroll
                    for (int j = 0; j < 4; ++j)
                        O[i][j] = fmaf(pm[i][cc], vm[cc][j], O[i][j]);
        }
    }

    // epilogue: normalize, store [B,S,H,Dh] (== [B,S,H*Dh] for out proj)
    const int b = bh >> 4, h = bh & 15;
#pragma unroll
    for (int i = 0; i < 4; ++i) {
        float inv = 1.0f / l_i[i];
        int srow = q0 + r0 + i;
        float4 o = make_float4(O[i][0] * inv, O[i][1] * inv, O[i][2] * inv, O[i][3] * inv);
        *(float4*)&ow[(((size_t)b * SEQ + srow) * NH + h) * DH + c0] = o;
    }
}

// ---------------------------------------------------------------------------
// Kernel 3: output projection, attn[4096,1024] @ wo[1024,1024] -> d_out
// ---------------------------------------------------------------------------
__global__ __launch_bounds__(256) void out_proj_kernel(
    const float* __restrict__ a, const float* __restrict__ w, float* __restrict__ out)
{
    const int m0 = blockIdx.y * 64;
    const int n0 = blockIdx.x * 64;
    const int t  = threadIdx.x;
    const int tx = t & 15, ty = t >> 4;
    const int r0 = ty * 4, c0 = tx * 4;

    __shared__ float As[16][64];
    __shared__ float Bs[16][64];

    float acc[4][4] = {};

    const int arow = t >> 2;
    const int aq   = (t & 3) * 4;
    const int brow = t >> 4;
    const int bc   = (t & 15) * 4;

    for (int k0 = 0; k0 < DM; k0 += 16) {
        float4 av = *(const float4*)&a[(size_t)(m0 + arow) * DM + k0 + aq];
        float4 bv = *(const float4*)&w[(size_t)(k0 + brow) * DM + n0 + bc];
        __syncthreads();
        As[aq + 0][arow] = av.x;
        As[aq + 1][arow] = av.y;
        As[aq + 2][arow] = av.z;
        As[aq + 3][arow] = av.w;
        *(float4*)&Bs[brow][bc] = bv;
        __syncthreads();
#pragma unroll
        for (int kk = 0; kk < 16; ++kk) {
            float4 a4 = *(const float4*)&As[kk][r0];
            float4 b4 = *(const float4*)&Bs[kk][c0];
            float avv[4] = {a4.x, a4.y, a4.z, a4.w};
            float bvv[4] = {b4.x, b4.y, b4.z, b4.w};
#pragma unroll
            for (int i = 0; i < 4; ++i)
#pragma unroll
                for (int j = 0; j < 4; ++j)
                    acc[i][j] = fmaf(avv[i], bvv[j], acc[i][j]);
        }
    }

#pragma unroll
    for (int i = 0; i < 4; ++i) {
        float4 o = make_float4(acc[i][0], acc[i][1], acc[i][2], acc[i][3]);
        *(float4*)&out[(size_t)(m0 + r0 + i) * DM + n0 + c0] = o;
    }
}

extern "C" void kernel_launch(void* const* d_in, const int* in_sizes, int n_in,
                              void* d_out, int out_size, void* d_ws, size_t ws_size,
                              hipStream_t stream)
{
    const float* x    = (const float*)d_in[0];
    const float* fcos = (const float*)d_in[1];
    const float* fsin = (const float*)d_in[2];
    const float* wq   = (const float*)d_in[3];
    const float* wk   = (const float*)d_in[4];
    const float* wv   = (const float*)d_in[5];
    const float* wo   = (const float*)d_in[6];
    float* out = (float*)d_out;
    float* ws  = (float*)d_ws;

    const size_t SZ = (size_t)BSZ * NH * SEQ * DH;  // 4M elements
    float* qw = ws;
    float* kw = ws + SZ;
    float* vw = ws + 2 * SZ;
    float* aw = ws + 3 * SZ;

    qkv_rope_kernel<<<dim3(HD / 64, (BSZ * SEQ) / 64, 3), 256, 0, stream>>>(
        x, wq, wk, wv, fcos, fsin, qw, kw, vw);
    attn_kernel<<<dim3(SEQ / 64, BSZ * NH), 256, 0, stream>>>(qw, kw, vw, aw);
    out_proj_kernel<<<dim3(DM / 64, (BSZ * SEQ) / 64), 256, 0, stream>>>(aw, wo, out);
}

// Round 2
// 346.814 us; speedup vs baseline: 3.1684x; 3.1684x over previous
//
#include <hip/hip_runtime.h>
#include <math.h>

#define BSZ 2
#define SEQ 2048
#define NH 16
#define DH 64
#define DM 1024
#define HD 1024

typedef _Float16 h16;
typedef _Float16 half8 __attribute__((ext_vector_type(8)));
typedef float f32x4 __attribute__((ext_vector_type(4)));

__device__ __forceinline__ f32x4 mfma16(half8 a, half8 b, f32x4 c) {
    return __builtin_amdgcn_mfma_f32_16x16x32_f16(a, b, c, 0, 0, 0);
}

// ---------------------------------------------------------------------------
// Precompute 1: x (fp32) -> x16 (f16). 4M elements.
// ---------------------------------------------------------------------------
__global__ __launch_bounds__(256) void cvt_x_kernel(const float* __restrict__ x,
                                                    h16* __restrict__ x16)
{
    int i = (blockIdx.x * 256 + threadIdx.x) * 8;
    float4 a = *(const float4*)&x[i];
    float4 b = *(const float4*)&x[i + 4];
    half8 o;
    o[0] = (h16)a.x; o[1] = (h16)a.y; o[2] = (h16)a.z; o[3] = (h16)a.w;
    o[4] = (h16)b.x; o[5] = (h16)b.y; o[6] = (h16)b.z; o[7] = (h16)b.w;
    *(half8*)&x16[i] = o;
}

// ---------------------------------------------------------------------------
// Precompute 2: W[k][n] fp32 -> WT_hi/WT_lo[n][k] f16 (split), 4 matrices.
// ---------------------------------------------------------------------------
__global__ __launch_bounds__(256) void wtrans_kernel(
    const float* __restrict__ wq, const float* __restrict__ wk,
    const float* __restrict__ wv, const float* __restrict__ wo,
    h16* __restrict__ wthi, h16* __restrict__ wtlo)
{
    const float* w = (blockIdx.z == 0) ? wq : (blockIdx.z == 1) ? wk
                   : (blockIdx.z == 2) ? wv : wo;
    h16* ohi = wthi + (size_t)blockIdx.z * DM * DM;
    h16* olo = wtlo + (size_t)blockIdx.z * DM * DM;
    __shared__ float tile[64][68];
    const int k0 = blockIdx.y * 64, n0 = blockIdx.x * 64;
    const int t = threadIdx.x;
    const int r = t >> 2, c4 = (t & 3) * 16;
#pragma unroll
    for (int i = 0; i < 16; i += 4) {
        float4 v = *(const float4*)&w[(size_t)(k0 + r) * DM + n0 + c4 + i];
        tile[r][c4 + i + 0] = v.x; tile[r][c4 + i + 1] = v.y;
        tile[r][c4 + i + 2] = v.z; tile[r][c4 + i + 3] = v.w;
    }
    __syncthreads();
#pragma unroll
    for (int g = 0; g < 2; ++g) {
        half8 hh, ll;
#pragma unroll
        for (int j = 0; j < 8; ++j) {
            float v = tile[c4 + g * 8 + j][r];
            h16 hi = (h16)v;
            hh[j] = hi;
            ll[j] = (h16)(v - (float)hi);
        }
        *(half8*)&ohi[(size_t)(n0 + r) * DM + k0 + c4 + g * 8] = hh;
        *(half8*)&olo[(size_t)(n0 + r) * DM + k0 + c4 + g * 8] = ll;
    }
}

// ---------------------------------------------------------------------------
// Kernel 1: QKV projection + RoPE via MFMA (f16, B-side hi/lo split).
// 128x128 tile, BK=32, 256 threads = 4 waves, wave-tile 64x64 (4x4 MFMAs).
// z=0: Q (rope, scale folded, split hi/lo); z=1: K (rope, f16);
// z=2: V -> transposed [B,H,D,S] f16 via LDS.
// ---------------------------------------------------------------------------
#define LDK 40  // padded stride (halfs) for [128][32] LDS tiles

__global__ __launch_bounds__(256) void qkv_kernel(
    const h16* __restrict__ x16,
    const h16* __restrict__ wthi, const h16* __restrict__ wtlo,
    const float* __restrict__ fcos, const float* __restrict__ fsin,
    h16* __restrict__ Qh, h16* __restrict__ Ql,
    h16* __restrict__ K16, h16* __restrict__ VT16)
{
    const int z = blockIdx.z;
    const h16* __restrict__ bh_ = wthi + (size_t)z * DM * DM;
    const h16* __restrict__ bl_ = wtlo + (size_t)z * DM * DM;

    // As/Bhs/Bls overlap Vt (Vt used only after the K-loop, with a barrier).
    __shared__ h16 smem[17408];  // 34816 B
    h16* As  = smem;              // 128*40 = 5120
    h16* Bhs = smem + 5120;
    h16* Bls = smem + 10240;
    h16* Vt  = smem;              // 128*136 = 17408 (z==2 epilogue only)

    const int m0 = blockIdx.y * 128;
    const int n0 = blockIdx.x * 128;
    const int t  = threadIdx.x;
    const int w  = t >> 6, ln = t & 63;
    const int L  = ln & 15, U = ln >> 4;
    const int wm = (w >> 1) * 64, wn = (w & 1) * 64;

    f32x4 acc[4][4];
#pragma unroll
    for (int i = 0; i < 4; ++i)
#pragma unroll
        for (int j = 0; j < 4; ++j) acc[i][j] = (f32x4)0.0f;

    for (int k0 = 0; k0 < DM; k0 += 32) {
        __syncthreads();
#pragma unroll
        for (int cc = 0; cc < 2; ++cc) {
            int c = t * 2 + cc;              // 0..511
            int row = c >> 2, col = (c & 3) * 8;
            *(half8*)&As[row * LDK + col]  = *(const half8*)&x16[(size_t)(m0 + row) * DM + k0 + col];
            *(half8*)&Bhs[row * LDK + col] = *(const half8*)&bh_[(size_t)(n0 + row) * DM + k0 + col];
            *(half8*)&Bls[row * LDK + col] = *(const half8*)&bl_[(size_t)(n0 + row) * DM + k0 + col];
        }
        __syncthreads();

        half8 af[4], bhf[4], blf[4];
#pragma unroll
        for (int mt = 0; mt < 4; ++mt)
            af[mt] = *(const half8*)&As[(wm + mt * 16 + L) * LDK + U * 8];
#pragma unroll
        for (int nt = 0; nt < 4; ++nt) {
            bhf[nt] = *(const half8*)&Bhs[(wn + nt * 16 + L) * LDK + U * 8];
            blf[nt] = *(const half8*)&Bls[(wn + nt * 16 + L) * LDK + U * 8];
        }
#pragma unroll
        for (int mt = 0; mt < 4; ++mt)
#pragma unroll
            for (int nt = 0; nt < 4; ++nt) {
                acc[mt][nt] = mfma16(af[mt], bhf[nt], acc[mt][nt]);
                acc[mt][nt] = mfma16(af[mt], blf[nt], acc[mt][nt]);
            }
    }

    const int b = m0 >> 11;
    const int sbase = m0 & 2047;

    if (z < 2) {
        const float sc = (z == 0) ? 0.125f * 1.44269504088896f : 1.0f;
#pragma unroll
        for (int mt = 0; mt < 4; ++mt)
#pragma unroll
            for (int nt = 0; nt < 4; ++nt)
#pragma unroll
                for (int r = 0; r < 4; ++r) {
                    float v = acc[mt][nt][r];
                    float p = __shfl_xor(v, 1, 64);
                    int nloc = wn + nt * 16 + L;
                    int n = n0 + nloc;
                    int d = n & 63, h = n >> 6;
                    int srow = sbase + wm + mt * 16 + U * 4 + r;
                    int pd = d >> 1;
                    float cv = fcos[srow * 32 + pd];
                    float sv = fsin[srow * 32 + pd];
                    float o = (d & 1) ? (p * sv + v * cv) : (v * cv - p * sv);
                    o *= sc;
                    size_t addr = ((size_t)(b * NH + h) * SEQ + srow) * DH + d;
                    if (z == 0) {
                        h16 hi = (h16)o;
                        Qh[addr] = hi;
                        Ql[addr] = (h16)(o - (float)hi);
                    } else {
                        K16[addr] = (h16)o;
                    }
                }
    } else {
        __syncthreads();  // all frag reads of smem done before Vt reuse
#pragma unroll
        for (int mt = 0; mt < 4; ++mt)
#pragma unroll
            for (int nt = 0; nt < 4; ++nt)
#pragma unroll
                for (int r = 0; r < 4; ++r) {
                    int nloc = wn + nt * 16 + L;
                    int sloc = wm + mt * 16 + U * 4 + r;
                    Vt[nloc * 136 + sloc] = (h16)acc[mt][nt][r];
                }
        __syncthreads();
#pragma unroll
        for (int i = 0; i < 8; ++i) {
            int c = i * 256 + t;     // 0..2047
            int dl = c >> 4;         // 0..127
            int s8 = (c & 15) * 8;
            half8 vv = *(const half8*)&Vt[dl * 136 + s8];
            int n = n0 + dl;
            int d = n & 63, h = n >> 6;
            *(half8*)&VT16[((size_t)(b * NH + h) * DH + d) * SEQ + sbase + s8] = vv;
        }
    }
}

// ---------------------------------------------------------------------------
// Kernel 2: flash attention, MFMA f16. Qt=128 (block), Kt=64 tiles.
// 4 waves; wave owns 32 q-rows. Q-frags live in registers (hi/lo, 2-product
// QK^T); K/V^T staged in LDS; P via LDS (f16) into PV (pure f16).
// ---------------------------------------------------------------------------
#define LDA 80  // padded stride (halfs) for 64-half rows

__global__ __launch_bounds__(256) void attn_kernel(
    const h16* __restrict__ Qh, const h16* __restrict__ Ql,
    const h16* __restrict__ K16, const h16* __restrict__ VT16,
    h16* __restrict__ A16)
{
    __shared__ h16 Ks[64 * LDA];
    __shared__ h16 Vs[64 * LDA];
    __shared__ h16 Ps[128 * LDA];

    const int t = threadIdx.x, w = t >> 6, ln = t & 63;
    const int L = ln & 15, U = ln >> 4;
    const int q0 = blockIdx.x * 128;
    const int bh = blockIdx.y;
    const size_t base = (size_t)bh * SEQ * DH;

    // Q fragments direct from global (rows = this wave's 32 q-rows)
    half8 qf[2][2][2];
#pragma unroll
    for (int mtt = 0; mtt < 2; ++mtt)
#pragma unroll
        for (int ks = 0; ks < 2; ++ks) {
            size_t ga = base + (size_t)(q0 + w * 32 + mtt * 16 + L) * DH + ks * 32 + U * 8;
            qf[mtt][ks][0] = *(const half8*)&Qh[ga];
            qf[mtt][ks][1] = *(const half8*)&Ql[ga];
        }

    f32x4 O[2][4];
    float m_i[2][4], l_i[2][4];
#pragma unroll
    for (int i = 0; i < 2; ++i)
#pragma unroll
        for (int r = 0; r < 4; ++r) { m_i[i][r] = -1e30f; l_i[i][r] = 0.0f; }
#pragma unroll
    for (int i = 0; i < 2; ++i)
#pragma unroll
        for (int j = 0; j < 4; ++j) O[i][j] = (f32x4)0.0f;

    for (int j0 = 0; j0 < SEQ; j0 += 64) {
        __syncthreads();  // prior PV reads done before restaging K/V
#pragma unroll
        for (int cc = 0; cc < 2; ++cc) {
            int c = t * 2 + cc;              // 0..511
            int row = c >> 3, col = (c & 7) * 8;
            *(half8*)&Ks[row * LDA + col] = *(const half8*)&K16[base + (size_t)(j0 + row) * DH + col];
            *(half8*)&Vs[row * LDA + col] = *(const half8*)&VT16[base + (size_t)row * SEQ + j0 + col];
        }
        __syncthreads();

        // S = Q K^T (2-product split on Q)
        f32x4 S[2][4];
#pragma unroll
        for (int i = 0; i < 2; ++i)
#pragma unroll
            for (int j = 0; j < 4; ++j) S[i][j] = (f32x4)0.0f;
        half8 kf[4][2];
#pragma unroll
        for (int nt = 0; nt < 4; ++nt)
#pragma unroll
            for (int ks = 0; ks < 2; ++ks)
                kf[nt][ks] = *(const half8*)&Ks[(nt * 16 + L) * LDA + ks * 32 + U * 8];
#pragma unroll
        for (int mtt = 0; mtt < 2; ++mtt)
#pragma unroll
            for (int nt = 0; nt < 4; ++nt)
#pragma unroll
                for (int ks = 0; ks < 2; ++ks) {
                    S[mtt][nt] = mfma16(qf[mtt][ks][0], kf[nt][ks], S[mtt][nt]);
                    S[mtt][nt] = mfma16(qf[mtt][ks][1], kf[nt][ks], S[mtt][nt]);
                }

        // online softmax (rows of this wave; exp2 domain, scale pre-folded)
#pragma unroll
        for (int mtt = 0; mtt < 2; ++mtt)
#pragma unroll
            for (int r = 0; r < 4; ++r) {
                float mx = fmaxf(fmaxf(S[mtt][0][r], S[mtt][1][r]),
                                 fmaxf(S[mtt][2][r], S[mtt][3][r]));
#pragma unroll
                for (int off = 1; off < 16; off <<= 1)
                    mx = fmaxf(mx, __shfl_xor(mx, off, 64));
                float mnew = fmaxf(m_i[mtt][r], mx);
                float alpha = exp2f(m_i[mtt][r] - mnew);
                float rs = 0.0f, pv[4];
#pragma unroll
                for (int nt = 0; nt < 4; ++nt) {
                    pv[nt] = exp2f(S[mtt][nt][r] - mnew);
                    rs += pv[nt];
                }
#pragma unroll
                for (int off = 1; off < 16; off <<= 1)
                    rs += __shfl_xor(rs, off, 64);
                m_i[mtt][r] = mnew;
                l_i[mtt][r] = l_i[mtt][r] * alpha + rs;
                int prow = (w * 32 + mtt * 16 + U * 4 + r) * LDA;
#pragma unroll
                for (int nt = 0; nt < 4; ++nt)
                    Ps[prow + nt * 16 + L] = (h16)pv[nt];
#pragma unroll
                for (int nt = 0; nt < 4; ++nt) O[mtt][nt][r] *= alpha;
            }
        __syncthreads();  // Ps visible (same wave rows, but keep it safe)

        // O += P V
        half8 pf[2][2], vf[4][2];
#pragma unroll
        for (int mtt = 0; mtt < 2; ++mtt)
#pragma unroll
            for (int ks = 0; ks < 2; ++ks)
                pf[mtt][ks] = *(const half8*)&Ps[(w * 32 + mtt * 16 + L) * LDA + ks * 32 + U * 8];
#pragma unroll
        for (int nt = 0; nt < 4; ++nt)
#pragma unroll
            for (int ks = 0; ks < 2; ++ks)
                vf[nt][ks] = *(const half8*)&Vs[(nt * 16 + L) * LDA + ks * 32 + U * 8];
#pragma unroll
        for (int mtt = 0; mtt < 2; ++mtt)
#pragma unroll
            for (int nt = 0; nt < 4; ++nt)
#pragma unroll
                for (int ks = 0; ks < 2; ++ks)
                    O[mtt][nt] = mfma16(pf[mtt][ks], vf[nt][ks], O[mtt][nt]);
    }

    // epilogue: normalize, write f16 [B,S,H*Dh]
    const int b = bh >> 4, h = bh & 15;
#pragma unroll
    for (int mtt = 0; mtt < 2; ++mtt)
#pragma unroll
        for (int r = 0; r < 4; ++r) {
            float inv = 1.0f / l_i[mtt][r];
            int s = q0 + w * 32 + mtt * 16 + U * 4 + r;
#pragma unroll
            for (int nt = 0; nt < 4; ++nt) {
                int d = nt * 16 + L;
                A16[(size_t)(b * SEQ + s) * HD + h * DH + d] = (h16)(O[mtt][nt][r] * inv);
            }
        }
}

// ---------------------------------------------------------------------------
// Kernel 3: output projection, MFMA f16 (B-side hi/lo split), fp32 out.
// ---------------------------------------------------------------------------
__global__ __launch_bounds__(256) void oproj_kernel(
    const h16* __restrict__ A16,
    const h16* __restrict__ bh_, const h16* __restrict__ bl_,
    float* __restrict__ out)
{
    __shared__ h16 As[128 * LDK];
    __shared__ h16 Bhs[128 * LDK];
    __shared__ h16 Bls[128 * LDK];

    const int m0 = blockIdx.y * 128;
    const int n0 = blockIdx.x * 128;
    const int t  = threadIdx.x;
    const int w  = t >> 6, ln = t & 63;
    const int L  = ln & 15, U = ln >> 4;
    const int wm = (w >> 1) * 64, wn = (w & 1) * 64;

    f32x4 acc[4][4];
#pragma unroll
    for (int i = 0; i < 4; ++i)
#pragma unroll
        for (int j = 0; j < 4; ++j) acc[i][j] = (f32x4)0.0f;

    for (int k0 = 0; k0 < DM; k0 += 32) {
        __syncthreads();
#pragma unroll
        for (int cc = 0; cc < 2; ++cc) {
            int c = t * 2 + cc;
            int row = c >> 2, col = (c & 3) * 8;
            *(half8*)&As[row * LDK + col]  = *(const half8*)&A16[(size_t)(m0 + row) * DM + k0 + col];
            *(half8*)&Bhs[row * LDK + col] = *(const half8*)&bh_[(size_t)(n0 + row) * DM + k0 + col];
            *(half8*)&Bls[row * LDK + col] = *(const half8*)&bl_[(size_t)(n0 + row) * DM + k0 + col];
        }
        __syncthreads();

        half8 af[4], bhf[4], blf[4];
#pragma unroll
        for (int mt = 0; mt < 4; ++mt)
            af[mt] = *(const half8*)&As[(wm + mt * 16 + L) * LDK + U * 8];
#pragma unroll
        for (int nt = 0; nt < 4; ++nt) {
            bhf[nt] = *(const half8*)&Bhs[(wn + nt * 16 + L) * LDK + U * 8];
            blf[nt] = *(const half8*)&Bls[(wn + nt * 16 + L) * LDK + U * 8];
        }
#pragma unroll
        for (int mt = 0; mt < 4; ++mt)
#pragma unroll
            for (int nt = 0; nt < 4; ++nt) {
                acc[mt][nt] = mfma16(af[mt], bhf[nt], acc[mt][nt]);
                acc[mt][nt] = mfma16(af[mt], blf[nt], acc[mt][nt]);
            }
    }

#pragma unroll
    for (int mt = 0; mt < 4; ++mt)
#pragma unroll
        for (int nt = 0; nt < 4; ++nt)
#pragma unroll
            for (int r = 0; r < 4; ++r) {
                int row = m0 + wm + mt * 16 + U * 4 + r;
                int col = n0 + wn + nt * 16 + L;
                out[(size_t)row * DM + col] = acc[mt][nt][r];
            }
}

extern "C" void kernel_launch(void* const* d_in, const int* in_sizes, int n_in,
                              void* d_out, int out_size, void* d_ws, size_t ws_size,
                              hipStream_t stream)
{
    const float* x    = (const float*)d_in[0];
    const float* fcos = (const float*)d_in[1];
    const float* fsin = (const float*)d_in[2];
    const float* wq   = (const float*)d_in[3];
    const float* wk   = (const float*)d_in[4];
    const float* wv   = (const float*)d_in[5];
    const float* wo   = (const float*)d_in[6];
    float* out = (float*)d_out;

    const size_t M4 = (size_t)4 * 1024 * 1024;
    h16* x16  = (h16*)d_ws;        // 4M halfs
    h16* wthi = x16 + M4;          // 4M (4 matrices x 1M, [n][k])
    h16* wtlo = wthi + M4;         // 4M
    h16* Qh   = wtlo + M4;         // 4M
    h16* Ql   = Qh + M4;           // 4M
    h16* K16  = Ql + M4;           // 4M
    h16* VT16 = K16 + M4;          // 4M  ([B,H,D,S])
    h16* A16  = VT16 + M4;         // 4M  -> total 32M halfs = 64 MB

    cvt_x_kernel<<<2048, 256, 0, stream>>>(x, x16);
    wtrans_kernel<<<dim3(16, 16, 4), 256, 0, stream>>>(wq, wk, wv, wo, wthi, wtlo);
    qkv_kernel<<<dim3(8, 32, 3), 256, 0, stream>>>(x16, wthi, wtlo, fcos, fsin,
                                                   Qh, Ql, K16, VT16);
    attn_kernel<<<dim3(16, 32), 256, 0, stream>>>(Qh, Ql, K16, VT16, A16);
    oproj_kernel<<<dim3(8, 32), 256, 0, stream>>>(A16, wthi + 3 * (size_t)DM * DM,
                                                  wtlo + 3 * (size_t)DM * DM, out);
}

// Round 3
// 286.735 us; speedup vs baseline: 3.8322x; 1.2095x over previous
//
#include <hip/hip_runtime.h>
#include <math.h>

#define BSZ 2
#define SEQ 2048
#define NH 16
#define DH 64
#define DM 1024
#define HD 1024

typedef _Float16 h16;
typedef _Float16 half8 __attribute__((ext_vector_type(8)));
typedef _Float16 half4 __attribute__((ext_vector_type(4)));
typedef float f32x4 __attribute__((ext_vector_type(4)));

__device__ __forceinline__ f32x4 mfma16(half8 a, half8 b, f32x4 c) {
    return __builtin_amdgcn_mfma_f32_16x16x32_f16(a, b, c, 0, 0, 0);
}

// ---------------------------------------------------------------------------
// Precompute 1: x (fp32) -> x16 (f16). 4M elements.
// ---------------------------------------------------------------------------
__global__ __launch_bounds__(256) void cvt_x_kernel(const float* __restrict__ x,
                                                    h16* __restrict__ x16)
{
    int i = (blockIdx.x * 256 + threadIdx.x) * 8;
    float4 a = *(const float4*)&x[i];
    float4 b = *(const float4*)&x[i + 4];
    half8 o;
    o[0] = (h16)a.x; o[1] = (h16)a.y; o[2] = (h16)a.z; o[3] = (h16)a.w;
    o[4] = (h16)b.x; o[5] = (h16)b.y; o[6] = (h16)b.z; o[7] = (h16)b.w;
    *(half8*)&x16[i] = o;
}

// ---------------------------------------------------------------------------
// Precompute 2: W[k][n] fp32 -> WT_hi/WT_lo[n][k] f16 (split), 4 matrices.
// ---------------------------------------------------------------------------
__global__ __launch_bounds__(256) void wtrans_kernel(
    const float* __restrict__ wq, const float* __restrict__ wk,
    const float* __restrict__ wv, const float* __restrict__ wo,
    h16* __restrict__ wthi, h16* __restrict__ wtlo)
{
    const float* w = (blockIdx.z == 0) ? wq : (blockIdx.z == 1) ? wk
                   : (blockIdx.z == 2) ? wv : wo;
    h16* ohi = wthi + (size_t)blockIdx.z * DM * DM;
    h16* olo = wtlo + (size_t)blockIdx.z * DM * DM;
    __shared__ float tile[64][68];
    const int k0 = blockIdx.y * 64, n0 = blockIdx.x * 64;
    const int t = threadIdx.x;
    const int r = t >> 2, c4 = (t & 3) * 16;
#pragma unroll
    for (int i = 0; i < 16; i += 4) {
        float4 v = *(const float4*)&w[(size_t)(k0 + r) * DM + n0 + c4 + i];
        tile[r][c4 + i + 0] = v.x; tile[r][c4 + i + 1] = v.y;
        tile[r][c4 + i + 2] = v.z; tile[r][c4 + i + 3] = v.w;
    }
    __syncthreads();
#pragma unroll
    for (int g = 0; g < 2; ++g) {
        half8 hh, ll;
#pragma unroll
        for (int j = 0; j < 8; ++j) {
            float v = tile[c4 + g * 8 + j][r];
            h16 hi = (h16)v;
            hh[j] = hi;
            ll[j] = (h16)(v - (float)hi);
        }
        *(half8*)&ohi[(size_t)(n0 + r) * DM + k0 + c4 + g * 8] = hh;
        *(half8*)&olo[(size_t)(n0 + r) * DM + k0 + c4 + g * 8] = ll;
    }
}

// ---------------------------------------------------------------------------
// Kernel 1: QKV projection + RoPE via MFMA, C^T orientation (lane holds
// d-contiguous feature quads -> in-register RoPE, b64 stores).
// 128x128 tile, BK=32, 256 threads = 4 waves, wave-tile 64x64.
// z=0: Q (rope, scale, hi/lo split); z=1: K (rope); z=2: V -> [B,H,D,S].
// ---------------------------------------------------------------------------
#define LDK 40  // padded stride (halfs) for [128][32] LDS tiles

__global__ __launch_bounds__(256) void qkv_kernel(
    const h16* __restrict__ x16,
    const h16* __restrict__ wthi, const h16* __restrict__ wtlo,
    const float* __restrict__ fcos, const float* __restrict__ fsin,
    h16* __restrict__ Qh, h16* __restrict__ Ql,
    h16* __restrict__ K16, h16* __restrict__ VT16)
{
    const int z = blockIdx.z;
    const h16* __restrict__ bh_ = wthi + (size_t)z * DM * DM;
    const h16* __restrict__ bl_ = wtlo + (size_t)z * DM * DM;

    __shared__ h16 smem[17408];  // As/Bhs/Bls overlap Vt (epilogue only)
    h16* As  = smem;
    h16* Bhs = smem + 5120;
    h16* Bls = smem + 10240;
    h16* Vt  = smem;

    const int m0 = blockIdx.y * 128;   // s-rows
    const int n0 = blockIdx.x * 128;   // features
    const int t  = threadIdx.x;
    const int w  = t >> 6, ln = t & 63;
    const int L  = ln & 15, U = ln >> 4;
    const int wm = (w >> 1) * 64, wn = (w & 1) * 64;

    f32x4 acc[4][4];
#pragma unroll
    for (int i = 0; i < 4; ++i)
#pragma unroll
        for (int j = 0; j < 4; ++j) acc[i][j] = (f32x4)0.0f;

    for (int k0 = 0; k0 < DM; k0 += 32) {
        __syncthreads();
#pragma unroll
        for (int cc = 0; cc < 2; ++cc) {
            int c = t * 2 + cc;
            int row = c >> 2, col = (c & 3) * 8;
            *(half8*)&As[row * LDK + col]  = *(const half8*)&x16[(size_t)(m0 + row) * DM + k0 + col];
            *(half8*)&Bhs[row * LDK + col] = *(const half8*)&bh_[(size_t)(n0 + row) * DM + k0 + col];
            *(half8*)&Bls[row * LDK + col] = *(const half8*)&bl_[(size_t)(n0 + row) * DM + k0 + col];
        }
        __syncthreads();

        half8 af[4], bhf[4], blf[4];
#pragma unroll
        for (int mt = 0; mt < 4; ++mt)
            af[mt] = *(const half8*)&As[(wm + mt * 16 + L) * LDK + U * 8];
#pragma unroll
        for (int nt = 0; nt < 4; ++nt) {
            bhf[nt] = *(const half8*)&Bhs[(wn + nt * 16 + L) * LDK + U * 8];
            blf[nt] = *(const half8*)&Bls[(wn + nt * 16 + L) * LDK + U * 8];
        }
        // C^T: A=weights (m=feature), B=x (n=s-row)
#pragma unroll
        for (int mt = 0; mt < 4; ++mt)
#pragma unroll
            for (int nt = 0; nt < 4; ++nt) {
                acc[mt][nt] = mfma16(bhf[nt], af[mt], acc[mt][nt]);
                acc[mt][nt] = mfma16(blf[nt], af[mt], acc[mt][nt]);
            }
    }

    const int b = m0 >> 11;
    const int sbase = m0 & 2047;

    // acc[mt][nt][r]: feature n_local = wn+nt*16+U*4+r, s_local = wm+mt*16+L
    if (z < 2) {
        const float sc = (z == 0) ? 0.125f * 1.44269504088896f : 1.0f;
#pragma unroll
        for (int mt = 0; mt < 4; ++mt) {
            int s = sbase + wm + mt * 16 + L;
            const float* ct = &fcos[s * 32];
            const float* st = &fsin[s * 32];
#pragma unroll
            for (int nt = 0; nt < 4; ++nt) {
                int nl = n0 + wn + nt * 16 + U * 4;   // multiple of 4
                int d = nl & 63, h = nl >> 6;
                int pd = d >> 1;
                float cv0 = ct[pd], sv0 = st[pd];
                float cv1 = ct[pd + 1], sv1 = st[pd + 1];
                float v0 = acc[mt][nt][0], v1 = acc[mt][nt][1];
                float v2 = acc[mt][nt][2], v3 = acc[mt][nt][3];
                float o0 = (v0 * cv0 - v1 * sv0) * sc;
                float o1 = (v0 * sv0 + v1 * cv0) * sc;
                float o2 = (v2 * cv1 - v3 * sv1) * sc;
                float o3 = (v2 * sv1 + v3 * cv1) * sc;
                size_t addr = ((size_t)(b * NH + h) * SEQ + s) * DH + d;
                if (z == 0) {
                    half4 hh, ll;
                    hh[0] = (h16)o0; hh[1] = (h16)o1; hh[2] = (h16)o2; hh[3] = (h16)o3;
                    ll[0] = (h16)(o0 - (float)hh[0]);
                    ll[1] = (h16)(o1 - (float)hh[1]);
                    ll[2] = (h16)(o2 - (float)hh[2]);
                    ll[3] = (h16)(o3 - (float)hh[3]);
                    *(half4*)&Qh[addr] = hh;
                    *(half4*)&Ql[addr] = ll;
                } else {
                    half4 kk;
                    kk[0] = (h16)o0; kk[1] = (h16)o1; kk[2] = (h16)o2; kk[3] = (h16)o3;
                    *(half4*)&K16[addr] = kk;
                }
            }
        }
    } else {
        __syncthreads();  // all frag reads done before Vt reuse
#pragma unroll
        for (int mt = 0; mt < 4; ++mt)
#pragma unroll
            for (int nt = 0; nt < 4; ++nt)
#pragma unroll
                for (int r = 0; r < 4; ++r) {
                    int nloc = wn + nt * 16 + U * 4 + r;
                    int sloc = wm + mt * 16 + L;
                    Vt[nloc * 136 + sloc] = (h16)acc[mt][nt][r];
                }
        __syncthreads();
#pragma unroll
        for (int i = 0; i < 8; ++i) {
            int c = i * 256 + t;
            int dl = c >> 4;
            int s8 = (c & 15) * 8;
            half8 vv = *(const half8*)&Vt[dl * 136 + s8];
            int n = n0 + dl;
            int d = n & 63, h = n >> 6;
            *(half8*)&VT16[((size_t)(b * NH + h) * DH + d) * SEQ + sbase + s8] = vv;
        }
    }
}

// ---------------------------------------------------------------------------
// Kernel 2: flash attention, S^T formulation. 512 threads = 8 waves,
// Qt=128 (16 q-rows per wave), Kt=64. Softmax k-reduction in-register +
// 2 shuffles; P written as b64 packs; alpha/l broadcast via tiny LDS array.
// ---------------------------------------------------------------------------
#define LDA 80

__global__ __launch_bounds__(512, 4) void attn_kernel(
    const h16* __restrict__ Qh, const h16* __restrict__ Ql,
    const h16* __restrict__ K16, const h16* __restrict__ VT16,
    h16* __restrict__ A16)
{
    __shared__ h16 Ks[64 * LDA];
    __shared__ h16 Vs[64 * LDA];
    __shared__ h16 Ps[128 * LDA];
    __shared__ float aL[128];

    const int t = threadIdx.x, w = t >> 6, ln = t & 63;
    const int L = ln & 15, U = ln >> 4;
    const int q0 = blockIdx.x * 128;
    const int bh = blockIdx.y;
    const size_t base = (size_t)bh * SEQ * DH;

    // Q fragments (wave's 16 q-rows), hi/lo
    half8 qfh[2], qfl[2];
#pragma unroll
    for (int ks = 0; ks < 2; ++ks) {
        size_t ga = base + (size_t)(q0 + w * 16 + L) * DH + ks * 32 + U * 8;
        qfh[ks] = *(const half8*)&Qh[ga];
        qfl[ks] = *(const half8*)&Ql[ga];
    }

    f32x4 O[4];
#pragma unroll
    for (int j = 0; j < 4; ++j) O[j] = (f32x4)0.0f;
    float m_i = -1e30f, l_i = 0.0f;

    const int srow = t >> 3, scol = (t & 7) * 8;
    const h16* kg = &K16[base + (size_t)srow * DH + scol];
    const h16* vg = &VT16[base + (size_t)srow * SEQ + scol];

    for (int j0 = 0; j0 < SEQ; j0 += 64) {
        __syncthreads();
        *(half8*)&Ks[srow * LDA + scol] = *(const half8*)&kg[(size_t)j0 * DH];
        *(half8*)&Vs[srow * LDA + scol] = *(const half8*)&vg[j0];
        __syncthreads();

        // S^T = K Q^T : S[nt] rows = kpos (nt*16+U*4+r), col = q (w*16+L)
        f32x4 S[4];
#pragma unroll
        for (int nt = 0; nt < 4; ++nt) S[nt] = (f32x4)0.0f;
#pragma unroll
        for (int nt = 0; nt < 4; ++nt)
#pragma unroll
            for (int ks = 0; ks < 2; ++ks) {
                half8 kf = *(const half8*)&Ks[(nt * 16 + L) * LDA + ks * 32 + U * 8];
                S[nt] = mfma16(kf, qfh[ks], S[nt]);
                S[nt] = mfma16(kf, qfl[ks], S[nt]);
            }

        // online softmax: lane owns column q = w*16+L (k subset in regs)
        float mx = -1e30f;
#pragma unroll
        for (int nt = 0; nt < 4; ++nt)
#pragma unroll
            for (int r = 0; r < 4; ++r) mx = fmaxf(mx, S[nt][r]);
        mx = fmaxf(mx, __shfl_xor(mx, 16, 64));
        mx = fmaxf(mx, __shfl_xor(mx, 32, 64));
        float mnew  = fmaxf(m_i, mx);
        float alpha = exp2f(m_i - mnew);
        float rs = 0.0f;
        half4 pq[4];
#pragma unroll
        for (int nt = 0; nt < 4; ++nt) {
            float p0 = exp2f(S[nt][0] - mnew);
            float p1 = exp2f(S[nt][1] - mnew);
            float p2 = exp2f(S[nt][2] - mnew);
            float p3 = exp2f(S[nt][3] - mnew);
            rs += (p0 + p1) + (p2 + p3);
            pq[nt][0] = (h16)p0; pq[nt][1] = (h16)p1;
            pq[nt][2] = (h16)p2; pq[nt][3] = (h16)p3;
        }
        rs += __shfl_xor(rs, 16, 64);
        rs += __shfl_xor(rs, 32, 64);
        m_i = mnew;
        l_i = l_i * alpha + rs;
#pragma unroll
        for (int nt = 0; nt < 4; ++nt)
            *(half4*)&Ps[(w * 16 + L) * LDA + nt * 16 + U * 4] = pq[nt];
        if (U == 0) aL[w * 16 + L] = alpha;

        // rescale O by alpha of q-row U*4+r (broadcast via LDS)
        f32x4 a4 = *(const f32x4*)&aL[w * 16 + U * 4];
#pragma unroll
        for (int nt = 0; nt < 4; ++nt) O[nt] *= a4;

        // O += P V  (A=P rows q, B=V rows d)
        half8 pf0 = *(const half8*)&Ps[(w * 16 + L) * LDA + U * 8];
        half8 pf1 = *(const half8*)&Ps[(w * 16 + L) * LDA + 32 + U * 8];
#pragma unroll
        for (int nt = 0; nt < 4; ++nt) {
            half8 vf0 = *(const half8*)&Vs[(nt * 16 + L) * LDA + U * 8];
            O[nt] = mfma16(pf0, vf0, O[nt]);
            half8 vf1 = *(const half8*)&Vs[(nt * 16 + L) * LDA + 32 + U * 8];
            O[nt] = mfma16(pf1, vf1, O[nt]);
        }
    }

    // epilogue: normalize (1/l broadcast), store f16 [B,S,H*Dh]
    if (U == 0) aL[w * 16 + L] = 1.0f / l_i;
    f32x4 li4 = *(const f32x4*)&aL[w * 16 + U * 4];
    const int b = bh >> 4, h = bh & 15;
#pragma unroll
    for (int nt = 0; nt < 4; ++nt)
#pragma unroll
        for (int r = 0; r < 4; ++r) {
            int s = q0 + w * 16 + U * 4 + r;
            int d = nt * 16 + L;
            A16[(size_t)(b * SEQ + s) * HD + h * DH + d] = (h16)(O[nt][r] * li4[r]);
        }
}

// ---------------------------------------------------------------------------
// Kernel 3: output projection, 128x64 tiles (512 blocks), hi/lo split B.
// ---------------------------------------------------------------------------
__global__ __launch_bounds__(256) void oproj_kernel(
    const h16* __restrict__ A16,
    const h16* __restrict__ bh_, const h16* __restrict__ bl_,
    float* __restrict__ out)
{
    __shared__ h16 As[128 * LDK];
    __shared__ h16 Bhs[64 * LDK];
    __shared__ h16 Bls[64 * LDK];

    const int m0 = blockIdx.y * 128;
    const int n0 = blockIdx.x * 64;
    const int t  = threadIdx.x;
    const int w  = t >> 6, ln = t & 63;
    const int L  = ln & 15, U = ln >> 4;

    f32x4 acc[2][4];
#pragma unroll
    for (int i = 0; i < 2; ++i)
#pragma unroll
        for (int j = 0; j < 4; ++j) acc[i][j] = (f32x4)0.0f;

    const int rb = t >> 2, cb = (t & 3) * 8;

    for (int k0 = 0; k0 < DM; k0 += 32) {
        __syncthreads();
#pragma unroll
        for (int cc = 0; cc < 2; ++cc) {
            int c = cc * 256 + t;
            int row = c >> 2, col = (c & 3) * 8;
            *(half8*)&As[row * LDK + col] = *(const half8*)&A16[(size_t)(m0 + row) * DM + k0 + col];
        }
        *(half8*)&Bhs[rb * LDK + cb] = *(const half8*)&bh_[(size_t)(n0 + rb) * DM + k0 + cb];
        *(half8*)&Bls[rb * LDK + cb] = *(const half8*)&bl_[(size_t)(n0 + rb) * DM + k0 + cb];
        __syncthreads();

        half8 af[2], bhf[4], blf[4];
#pragma unroll
        for (int mt = 0; mt < 2; ++mt)
            af[mt] = *(const half8*)&As[(w * 32 + mt * 16 + L) * LDK + U * 8];
#pragma unroll
        for (int nt = 0; nt < 4; ++nt) {
            bhf[nt] = *(const half8*)&Bhs[(nt * 16 + L) * LDK + U * 8];
            blf[nt] = *(const half8*)&Bls[(nt * 16 + L) * LDK + U * 8];
        }
#pragma unroll
        for (int mt = 0; mt < 2; ++mt)
#pragma unroll
            for (int nt = 0; nt < 4; ++nt) {
                acc[mt][nt] = mfma16(af[mt], bhf[nt], acc[mt][nt]);
                acc[mt][nt] = mfma16(af[mt], blf[nt], acc[mt][nt]);
            }
    }

#pragma unroll
    for (int mt = 0; mt < 2; ++mt)
#pragma unroll
        for (int nt = 0; nt < 4; ++nt)
#pragma unroll
            for (int r = 0; r < 4; ++r) {
                int row = m0 + w * 32 + mt * 16 + U * 4 + r;
                int col = n0 + nt * 16 + L;
                out[(size_t)row * DM + col] = acc[mt][nt][r];
            }
}

extern "C" void kernel_launch(void* const* d_in, const int* in_sizes, int n_in,
                              void* d_out, int out_size, void* d_ws, size_t ws_size,
                              hipStream_t stream)
{
    const float* x    = (const float*)d_in[0];
    const float* fcos = (const float*)d_in[1];
    const float* fsin = (const float*)d_in[2];
    const float* wq   = (const float*)d_in[3];
    const float* wk   = (const float*)d_in[4];
    const float* wv   = (const float*)d_in[5];
    const float* wo   = (const float*)d_in[6];
    float* out = (float*)d_out;

    const size_t M4 = (size_t)4 * 1024 * 1024;
    h16* x16  = (h16*)d_ws;
    h16* wthi = x16 + M4;
    h16* wtlo = wthi + M4;
    h16* Qh   = wtlo + M4;
    h16* Ql   = Qh + M4;
    h16* K16  = Ql + M4;
    h16* VT16 = K16 + M4;
    h16* A16  = VT16 + M4;

    cvt_x_kernel<<<2048, 256, 0, stream>>>(x, x16);
    wtrans_kernel<<<dim3(16, 16, 4), 256, 0, stream>>>(wq, wk, wv, wo, wthi, wtlo);
    qkv_kernel<<<dim3(8, 32, 3), 256, 0, stream>>>(x16, wthi, wtlo, fcos, fsin,
                                                   Qh, Ql, K16, VT16);
    attn_kernel<<<dim3(16, 32), 512, 0, stream>>>(Qh, Ql, K16, VT16, A16);
    oproj_kernel<<<dim3(16, 32), 256, 0, stream>>>(A16, wthi + 3 * (size_t)DM * DM,
                                                   wtlo + 3 * (size_t)DM * DM, out);
}